// Round 2
// baseline (221.038 us; speedup 1.0000x reference)
//
#include <hip/hip_runtime.h>
#include <math.h>

// Problem sizes (fixed by reference setup_inputs)
#define BATCH 8
#define NPTS  8192   // pred/full points per batch
#define PPTS  2048   // partial points per batch
#define DLAT  512    // latent dim

// Workspace layout (all in d_ws, re-poisoned to 0xAA before every launch,
// so init_kernel must rewrite everything we read):
//   uint  min_pf [BATCH*NPTS]   min sq dist pred->full
//   uint  min_fp [BATCH*NPTS]   min sq dist full->pred
//   uint  min_fid[BATCH*PPTS]   min sq dist partial->pred
//   float acc[4]                sums: pf, fp, fid, kl
#define OFF_PF   0
#define OFF_FP   (BATCH * NPTS)
#define OFF_FID  (2 * BATCH * NPTS)
#define OFF_ACC  (2 * BATCH * NPTS + BATCH * PPTS)
#define WS_ELEMS (OFF_ACC + 4)

// ---------------------------------------------------------------- init
__global__ void init_kernel(unsigned int* __restrict__ ws) {
    int i = blockIdx.x * blockDim.x + threadIdx.x;
    if (i < 2 * BATCH * NPTS + BATCH * PPTS) ws[i] = 0x7F800000u;  // +inf
    if (i < 4) ((float*)(ws + OFF_ACC))[i] = 0.0f;
}

// ---------------------------------------------------------------- min pass
// Grid: x = column chunk (8 chunks of 1024 cols), y = row tile (0..7 pred->full,
// 8..15 full->pred, 16..17 partial->pred), z = batch. Block = 256 threads,
// 4 row points per thread (1024 rows/block). Columns staged through LDS,
// broadcast-read (conflict-free). Row mins merged across column chunks with
// atomicMin on uint bit pattern (valid: sq >= 0, so uint order == float order).
__global__ __launch_bounds__(256) void minpass_kernel(
        const float* __restrict__ pred,
        const float* __restrict__ full,
        const float* __restrict__ partial,
        unsigned int* __restrict__ ws) {
    const int b      = blockIdx.z;
    const int tile   = blockIdx.y;
    const int cchunk = blockIdx.x;

    const float* rows;
    const float* cols;
    unsigned int* mins;
    int nRows, rowTile;
    if (tile < 8)       { rows = pred;    cols = full; mins = ws + OFF_PF;  nRows = NPTS; rowTile = tile;      }
    else if (tile < 16) { rows = full;    cols = pred; mins = ws + OFF_FP;  nRows = NPTS; rowTile = tile - 8;  }
    else                { rows = partial; cols = pred; mins = ws + OFF_FID; nRows = PPTS; rowTile = tile - 16; }

    constexpr int RT = 4;    // row points per thread
    constexpr int BT = 256;  // threads per block
    const int t = threadIdx.x;

    float rx[RT], ry[RT], rz[RT], mn[RT];
    const int rowBase = b * nRows + rowTile * (BT * RT);
#pragma unroll
    for (int r = 0; r < RT; ++r) {
        const int idx = (rowBase + r * BT + t) * 3;
        rx[r] = rows[idx + 0];
        ry[r] = rows[idx + 1];
        rz[r] = rows[idx + 2];
        mn[r] = 3.4e38f;
    }

    __shared__ float sc[768];  // 256 column points, xyz interleaved
    const int colBase = (b * NPTS + cchunk * 1024) * 3;

    for (int cs = 0; cs < 1024; cs += 256) {
        __syncthreads();
        const int src = colBase + cs * 3;
        sc[t]       = cols[src + t];
        sc[t + 256] = cols[src + t + 256];
        sc[t + 512] = cols[src + t + 512];
        __syncthreads();
#pragma unroll 8
        for (int j = 0; j < 256; ++j) {
            const float X = sc[3 * j + 0];
            const float Y = sc[3 * j + 1];
            const float Z = sc[3 * j + 2];
#pragma unroll
            for (int r = 0; r < RT; ++r) {
                const float dx = rx[r] - X;
                const float dy = ry[r] - Y;
                const float dz = rz[r] - Z;
                const float sq = fmaf(dx, dx, fmaf(dy, dy, dz * dz));
                mn[r] = fminf(mn[r], sq);
            }
        }
    }

#pragma unroll
    for (int r = 0; r < RT; ++r)
        atomicMin(&mins[rowBase + r * BT + t], __float_as_uint(mn[r]));
}

// ---------------------------------------------------------------- reductions
__device__ __forceinline__ float waveReduceSum(float v) {
#pragma unroll
    for (int o = 32; o > 0; o >>= 1) v += __shfl_down(v, o, 64);
    return v;
}

__device__ __forceinline__ float blockReduceSum(float v) {
    __shared__ float wsum[4];
    const int lane = threadIdx.x & 63;
    const int wid  = threadIdx.x >> 6;
    v = waveReduceSum(v);
    if (lane == 0) wsum[wid] = v;
    __syncthreads();
    if (wid == 0) {
        v = (lane < ((int)blockDim.x >> 6)) ? wsum[lane] : 0.0f;
        v = waveReduceSum(v);
    }
    return v;
}

__global__ void reduce_sqrt_sum_kernel(const unsigned int* __restrict__ src,
                                       int n, float* __restrict__ acc,
                                       int accIdx) {
    float v = 0.0f;
    for (int i = blockIdx.x * blockDim.x + threadIdx.x; i < n;
         i += gridDim.x * blockDim.x)
        v += sqrtf(fmaxf(__uint_as_float(src[i]), 1e-12f));
    v = blockReduceSum(v);
    if (threadIdx.x == 0) atomicAdd(&acc[accIdx], v);
}

__global__ void kl_kernel(const float* __restrict__ mu,
                          const float* __restrict__ logvar,
                          float* __restrict__ acc) {
    float v = 0.0f;
    for (int i = blockIdx.x * blockDim.x + threadIdx.x; i < BATCH * DLAT;
         i += gridDim.x * blockDim.x) {
        const float m = mu[i];
        const float l = logvar[i];
        v += -0.5f * (1.0f + l - m * m - expf(l));
    }
    v = blockReduceSum(v);
    if (threadIdx.x == 0) atomicAdd(&acc[3], v);
}

__global__ void finalize_kernel(const float* __restrict__ acc,
                                float* __restrict__ out) {
    const float s_pf  = acc[0];
    const float s_fp  = acc[1];
    const float s_fid = acc[2];
    const float s_kl  = acc[3];
    const float cd  = 0.5f * (s_pf / (float)(BATCH * NPTS) +
                              s_fp / (float)(BATCH * NPTS));
    const float fid = s_fid / (float)(BATCH * PPTS);
    const float kl  = s_kl / (float)BATCH;
    out[0] = cd + 0.01f * kl + 0.5f * fid;  // CD_WEIGHT=1, BETA=0.01, FID_W=0.5
    out[1] = cd;
    out[2] = kl;
    out[3] = fid;
}

// ---------------------------------------------------------------- launch
extern "C" void kernel_launch(void* const* d_in, const int* in_sizes, int n_in,
                              void* d_out, int out_size, void* d_ws, size_t ws_size,
                              hipStream_t stream) {
    const float* pred    = (const float*)d_in[0];
    const float* full    = (const float*)d_in[1];
    const float* partial = (const float*)d_in[2];
    const float* mu      = (const float*)d_in[3];
    const float* logvar  = (const float*)d_in[4];
    float* out = (float*)d_out;

    unsigned int* ws  = (unsigned int*)d_ws;
    float*        acc = (float*)(ws + OFF_ACC);

    // 1. init workspace (WS_ELEMS = 147460 -> 576 blocks x 256 covers it)
    init_kernel<<<(WS_ELEMS + 255) / 256, 256, 0, stream>>>(ws);

    // 2. fused min-distance pass: 8 col chunks x (8+8+2) row tiles x 8 batches
    dim3 grid(8, 18, BATCH);
    minpass_kernel<<<grid, 256, 0, stream>>>(pred, full, partial, ws);

    // 3. reductions
    reduce_sqrt_sum_kernel<<<64, 256, 0, stream>>>(ws + OFF_PF,  BATCH * NPTS, acc, 0);
    reduce_sqrt_sum_kernel<<<64, 256, 0, stream>>>(ws + OFF_FP,  BATCH * NPTS, acc, 1);
    reduce_sqrt_sum_kernel<<<16, 256, 0, stream>>>(ws + OFF_FID, BATCH * PPTS, acc, 2);
    kl_kernel<<<4, 256, 0, stream>>>(mu, logvar, acc);

    // 4. finalize
    finalize_kernel<<<1, 64, 0, stream>>>(acc, out);
}

// Round 3
// 165.667 us; speedup vs baseline: 1.3342x; 1.3342x over previous
//
#include <hip/hip_runtime.h>
#include <math.h>

// Problem sizes (fixed by reference setup_inputs)
#define BATCH 8
#define NPTS  8192   // pred/full points per batch
#define PPTS  2048   // partial points per batch
#define DLAT  512    // latent dim

// Workspace layout (uint elements in d_ws; re-poisoned 0xAA every launch,
// init_kernel rewrites everything we read):
//   [OFF_PF ..)  uint  min sq dist pred->full   (BATCH*NPTS)
//   [OFF_FP ..)  uint  min sq dist full->pred   (BATCH*NPTS)
//   [OFF_FID..)  uint  min sq dist partial->pred(BATCH*PPTS)
//   [OFF_ACC..)  float acc[4]: sum_pf, sum_fp, sum_fid, sum_kl
//   [OFF_CNT]    uint  reduce-block completion counter
#define OFF_PF   0
#define OFF_FP   (BATCH * NPTS)
#define OFF_FID  (2 * BATCH * NPTS)
#define OFF_ACC  (2 * BATCH * NPTS + BATCH * PPTS)
#define OFF_CNT  (OFF_ACC + 4)
#define WS_ELEMS (OFF_CNT + 1)

// ---------------------------------------------------------------- init
__global__ void init_kernel(unsigned int* __restrict__ ws) {
    int i = blockIdx.x * blockDim.x + threadIdx.x;
    if (i < OFF_ACC) ws[i] = 0x7F800000u;  // +inf
    if (i < 4) ((float*)(ws + OFF_ACC))[i] = 0.0f;
    if (i == 0) ws[OFF_CNT] = 0u;
}

// ---------------------------------------------------------------- min pass
// Expanded form: sq = (cn - 2 r.c) + rn, rn hoisted outside the min.
// Grid: x = 16 column chunks of 512, y = row tile (0..3 pred->full,
// 4..7 full->pred, 8 partial->pred), z = batch. Block = 256 threads,
// RT=8 rows/thread (2048 rows/block). Columns staged in LDS as
// float4(x,y,z,|c|^2); broadcast ds_read_b128 per column (conflict-free).
// Cross-chunk merge: atomicMin on uint bit pattern (values clamped >= 0).
__global__ __launch_bounds__(256) void minpass_kernel(
        const float* __restrict__ pred,
        const float* __restrict__ full,
        const float* __restrict__ partial,
        unsigned int* __restrict__ ws) {
    const int b      = blockIdx.z;
    const int tile   = blockIdx.y;
    const int cchunk = blockIdx.x;

    const float* rows;
    const float* cols;
    unsigned int* mins;
    int nRows, rowTile;
    if (tile < 4)      { rows = pred;    cols = full; mins = ws + OFF_PF;  nRows = NPTS; rowTile = tile;     }
    else if (tile < 8) { rows = full;    cols = pred; mins = ws + OFF_FP;  nRows = NPTS; rowTile = tile - 4; }
    else               { rows = partial; cols = pred; mins = ws + OFF_FID; nRows = PPTS; rowTile = 0;        }

    constexpr int RT   = 8;    // rows per thread
    constexpr int BT   = 256;  // threads per block
    constexpr int COLS = 512;  // columns per chunk
    const int t = threadIdx.x;

    // Stage columns: float4(x, y, z, |c|^2)
    __shared__ float4 sc4[COLS];
    {
        const float* cbase = cols + (size_t)(b * NPTS + cchunk * COLS) * 3;
        for (int i = t; i < COLS; i += BT) {
            const float X = cbase[3 * i + 0];
            const float Y = cbase[3 * i + 1];
            const float Z = cbase[3 * i + 2];
            sc4[i] = make_float4(X, Y, Z, fmaf(X, X, fmaf(Y, Y, Z * Z)));
        }
    }

    // Row registers: -2x, -2y, -2z, |r|^2
    float m2x[RT], m2y[RT], m2z[RT], rn[RT], mn[RT];
    const int rowBase = b * nRows + rowTile * (BT * RT);
#pragma unroll
    for (int r = 0; r < RT; ++r) {
        const int idx = (rowBase + r * BT + t) * 3;
        const float X = rows[idx + 0];
        const float Y = rows[idx + 1];
        const float Z = rows[idx + 2];
        m2x[r] = -2.0f * X;
        m2y[r] = -2.0f * Y;
        m2z[r] = -2.0f * Z;
        rn[r]  = fmaf(X, X, fmaf(Y, Y, Z * Z));
        mn[r]  = 3.4e38f;
    }
    __syncthreads();

#pragma unroll 4
    for (int j = 0; j < COLS; ++j) {
        const float4 c = sc4[j];
#pragma unroll
        for (int r = 0; r < RT; ++r)
            mn[r] = fminf(mn[r],
                     fmaf(m2z[r], c.z, fmaf(m2y[r], c.y, fmaf(m2x[r], c.x, c.w))));
    }

#pragma unroll
    for (int r = 0; r < RT; ++r) {
        const float sq = fmaxf(mn[r] + rn[r], 0.0f);  // clamp: monotone, keeps uint order valid
        atomicMin(&mins[rowBase + r * BT + t], __float_as_uint(sq));
    }
}

// ---------------------------------------------------------------- reductions
__device__ __forceinline__ float waveReduceSum(float v) {
#pragma unroll
    for (int o = 32; o > 0; o >>= 1) v += __shfl_down(v, o, 64);
    return v;
}

__device__ __forceinline__ float blockReduceSum(float v) {
    __shared__ float wsum[4];
    const int lane = threadIdx.x & 63;
    const int wid  = threadIdx.x >> 6;
    v = waveReduceSum(v);
    if (lane == 0) wsum[wid] = v;
    __syncthreads();
    if (wid == 0) {
        v = (lane < ((int)blockDim.x >> 6)) ? wsum[lane] : 0.0f;
        v = waveReduceSum(v);
    }
    return v;
}

// One kernel for all reductions + finalize (last-block pattern).
// Blocks 0..63: pf (1024 elems each), 64..127: fp, 128..143: fid, 144: kl.
#define NRED_BLOCKS 145
__global__ __launch_bounds__(256) void reduce_finalize_kernel(
        unsigned int* __restrict__ ws,
        const float* __restrict__ mu,
        const float* __restrict__ logvar,
        float* __restrict__ out) {
    float* acc = (float*)(ws + OFF_ACC);
    unsigned int* cnt = ws + OFF_CNT;
    const int bid = blockIdx.x;
    const int t   = threadIdx.x;

    float v = 0.0f;
    int accIdx;
    if (bid < 144) {
        int base;
        if (bid < 64)       { accIdx = 0; base = OFF_PF  + bid * 1024;         }
        else if (bid < 128) { accIdx = 1; base = OFF_FP  + (bid - 64) * 1024;  }
        else                { accIdx = 2; base = OFF_FID + (bid - 128) * 1024; }
#pragma unroll
        for (int k = 0; k < 4; ++k)
            v += sqrtf(fmaxf(__uint_as_float(ws[base + k * 256 + t]), 1e-12f));
    } else {
        accIdx = 3;
#pragma unroll
        for (int k = 0; k < BATCH * DLAT / 256; ++k) {
            const int i = k * 256 + t;
            const float m = mu[i];
            const float l = logvar[i];
            v += -0.5f * (1.0f + l - m * m - expf(l));
        }
    }

    v = blockReduceSum(v);
    if (t == 0) {
        atomicAdd(&acc[accIdx], v);
        __threadfence();
        const unsigned int done = atomicAdd(cnt, 1u);
        if (done == NRED_BLOCKS - 1) {
            // Last block: all partial sums are in L2; read coherently via atomics.
            const float s_pf  = atomicAdd(&acc[0], 0.0f);
            const float s_fp  = atomicAdd(&acc[1], 0.0f);
            const float s_fid = atomicAdd(&acc[2], 0.0f);
            const float s_kl  = atomicAdd(&acc[3], 0.0f);
            const float cd  = 0.5f * (s_pf / (float)(BATCH * NPTS) +
                                      s_fp / (float)(BATCH * NPTS));
            const float fid = s_fid / (float)(BATCH * PPTS);
            const float kl  = s_kl / (float)BATCH;
            out[0] = cd + 0.01f * kl + 0.5f * fid;  // CD_W=1, BETA=0.01, FID_W=0.5
            out[1] = cd;
            out[2] = kl;
            out[3] = fid;
        }
    }
}

// ---------------------------------------------------------------- launch
extern "C" void kernel_launch(void* const* d_in, const int* in_sizes, int n_in,
                              void* d_out, int out_size, void* d_ws, size_t ws_size,
                              hipStream_t stream) {
    const float* pred    = (const float*)d_in[0];
    const float* full    = (const float*)d_in[1];
    const float* partial = (const float*)d_in[2];
    const float* mu      = (const float*)d_in[3];
    const float* logvar  = (const float*)d_in[4];
    float* out = (float*)d_out;

    unsigned int* ws = (unsigned int*)d_ws;

    // 1. init workspace
    init_kernel<<<(WS_ELEMS + 255) / 256, 256, 0, stream>>>(ws);

    // 2. fused min-distance pass: 16 col chunks x (4+4+1) row tiles x 8 batches
    dim3 grid(16, 9, BATCH);
    minpass_kernel<<<grid, 256, 0, stream>>>(pred, full, partial, ws);

    // 3. all reductions + finalize in one dispatch
    reduce_finalize_kernel<<<NRED_BLOCKS, 256, 0, stream>>>(ws, mu, logvar, out);
}

// Round 4
// 160.163 us; speedup vs baseline: 1.3801x; 1.0344x over previous
//
#include <hip/hip_runtime.h>
#include <math.h>

// Problem sizes (fixed by reference setup_inputs)
#define BATCH 8
#define NPTS  8192   // pred/full points per batch
#define PPTS  2048   // partial points per batch
#define DLAT  512    // latent dim

typedef float v2f __attribute__((ext_vector_type(2)));

// Workspace layout (uint elements in d_ws; re-poisoned 0xAA every launch,
// init_kernel rewrites everything we read):
//   [OFF_PF ..)  uint  min sq dist pred->full    (BATCH*NPTS)
//   [OFF_FP ..)  uint  min sq dist full->pred    (BATCH*NPTS)
//   [OFF_FID..)  uint  min sq dist partial->pred (BATCH*PPTS)
//   [OFF_ACC..)  float acc[4]: sum_pf, sum_fp, sum_fid, sum_kl
//   [OFF_CNT]    uint  reduce-block completion counter
#define OFF_PF   0
#define OFF_FP   (BATCH * NPTS)
#define OFF_FID  (2 * BATCH * NPTS)
#define OFF_ACC  (2 * BATCH * NPTS + BATCH * PPTS)
#define OFF_CNT  (OFF_ACC + 4)
#define WS_ELEMS (OFF_CNT + 1)

// ---------------------------------------------------------------- init
__global__ void init_kernel(unsigned int* __restrict__ ws) {
    int i = blockIdx.x * blockDim.x + threadIdx.x;
    if (i < OFF_ACC) ws[i] = 0x7F800000u;  // +inf
    if (i < 4) ((float*)(ws + OFF_ACC))[i] = 0.0f;
    if (i == 0) ws[OFF_CNT] = 0u;
}

// ---------------------------------------------------------------- min pass
// Expanded form sq = (cn - 2 r.c) + rn, rn hoisted outside the min.
// PACKED FP32: 2 columns per inner iteration via v2f (<2 x float>) so the
// backend can emit v_pk_fma_f32 (full-rate packed FP32, gfx90a+ lineage).
// Per 2 pairs: 3 pk_fma + 1 elementwise-min = 2.5 issue-slots/pair (was 4).
// Columns staged in LDS as SoA float2-of-column-pairs; all lanes read the
// same address -> broadcast, conflict-free. Horizontal min in epilogue.
// Cross-chunk merge: atomicMin on uint bit pattern (values clamped >= 0).
__global__ __launch_bounds__(256) void minpass_kernel(
        const float* __restrict__ pred,
        const float* __restrict__ full,
        const float* __restrict__ partial,
        unsigned int* __restrict__ ws) {
    const int b      = blockIdx.z;
    const int tile   = blockIdx.y;
    const int cchunk = blockIdx.x;

    const float* rows;
    const float* cols;
    unsigned int* mins;
    int nRows, rowTile;
    if (tile < 4)      { rows = pred;    cols = full; mins = ws + OFF_PF;  nRows = NPTS; rowTile = tile;     }
    else if (tile < 8) { rows = full;    cols = pred; mins = ws + OFF_FP;  nRows = NPTS; rowTile = tile - 4; }
    else               { rows = partial; cols = pred; mins = ws + OFF_FID; nRows = PPTS; rowTile = 0;        }

    constexpr int RT    = 8;    // rows per thread
    constexpr int BT    = 256;  // threads per block
    constexpr int CPAIR = 256;  // column pairs per chunk (512 columns)
    const int t = threadIdx.x;

    // Stage column pairs SoA: sx[i] = {x[2i], x[2i+1]}, etc. sw = |c|^2 pair.
    __shared__ v2f sx[CPAIR], sy[CPAIR], sz[CPAIR], sw[CPAIR];
    {
        const float* cbase = cols + (size_t)(b * NPTS + cchunk * 2 * CPAIR) * 3;
        for (int i = t; i < CPAIR; i += BT) {
            const float x0 = cbase[6 * i + 0], y0 = cbase[6 * i + 1], z0 = cbase[6 * i + 2];
            const float x1 = cbase[6 * i + 3], y1 = cbase[6 * i + 4], z1 = cbase[6 * i + 5];
            sx[i] = (v2f){x0, x1};
            sy[i] = (v2f){y0, y1};
            sz[i] = (v2f){z0, z1};
            sw[i] = (v2f){fmaf(x0, x0, fmaf(y0, y0, z0 * z0)),
                          fmaf(x1, x1, fmaf(y1, y1, z1 * z1))};
        }
    }

    // Row registers: -2x/-2y/-2z duplicated into both packed halves; |r|^2 scalar.
    v2f m2x[RT], m2y[RT], m2z[RT], mn2[RT];
    float rn[RT];
    const int rowBase = b * nRows + rowTile * (BT * RT);
#pragma unroll
    for (int r = 0; r < RT; ++r) {
        const int idx = (rowBase + r * BT + t) * 3;
        const float X = rows[idx + 0];
        const float Y = rows[idx + 1];
        const float Z = rows[idx + 2];
        m2x[r] = (v2f){-2.0f * X, -2.0f * X};
        m2y[r] = (v2f){-2.0f * Y, -2.0f * Y};
        m2z[r] = (v2f){-2.0f * Z, -2.0f * Z};
        rn[r]  = fmaf(X, X, fmaf(Y, Y, Z * Z));
        mn2[r] = (v2f){3.4e38f, 3.4e38f};
    }
    __syncthreads();

#pragma unroll 4
    for (int j = 0; j < CPAIR; ++j) {
        const v2f X = sx[j];
        const v2f Y = sy[j];
        const v2f Z = sz[j];
        const v2f W = sw[j];
#pragma unroll
        for (int r = 0; r < RT; ++r) {
            const v2f d = __builtin_elementwise_fma(m2z[r], Z,
                           __builtin_elementwise_fma(m2y[r], Y,
                            __builtin_elementwise_fma(m2x[r], X, W)));
            mn2[r] = __builtin_elementwise_min(mn2[r], d);
        }
    }

#pragma unroll
    for (int r = 0; r < RT; ++r) {
        const float m  = fminf(mn2[r].x, mn2[r].y);
        const float sq = fmaxf(m + rn[r], 0.0f);  // clamp: monotone, keeps uint order
        atomicMin(&mins[rowBase + r * BT + t], __float_as_uint(sq));
    }
}

// ---------------------------------------------------------------- reductions
__device__ __forceinline__ float waveReduceSum(float v) {
#pragma unroll
    for (int o = 32; o > 0; o >>= 1) v += __shfl_down(v, o, 64);
    return v;
}

__device__ __forceinline__ float blockReduceSum(float v) {
    __shared__ float wsum[4];
    const int lane = threadIdx.x & 63;
    const int wid  = threadIdx.x >> 6;
    v = waveReduceSum(v);
    if (lane == 0) wsum[wid] = v;
    __syncthreads();
    if (wid == 0) {
        v = (lane < ((int)blockDim.x >> 6)) ? wsum[lane] : 0.0f;
        v = waveReduceSum(v);
    }
    return v;
}

// One kernel for all reductions + finalize (last-block pattern).
// Blocks 0..63: pf (1024 elems each), 64..127: fp, 128..143: fid, 144: kl.
#define NRED_BLOCKS 145
__global__ __launch_bounds__(256) void reduce_finalize_kernel(
        unsigned int* __restrict__ ws,
        const float* __restrict__ mu,
        const float* __restrict__ logvar,
        float* __restrict__ out) {
    float* acc = (float*)(ws + OFF_ACC);
    unsigned int* cnt = ws + OFF_CNT;
    const int bid = blockIdx.x;
    const int t   = threadIdx.x;

    float v = 0.0f;
    int accIdx;
    if (bid < 144) {
        int base;
        if (bid < 64)       { accIdx = 0; base = OFF_PF  + bid * 1024;         }
        else if (bid < 128) { accIdx = 1; base = OFF_FP  + (bid - 64) * 1024;  }
        else                { accIdx = 2; base = OFF_FID + (bid - 128) * 1024; }
#pragma unroll
        for (int k = 0; k < 4; ++k)
            v += sqrtf(fmaxf(__uint_as_float(ws[base + k * 256 + t]), 1e-12f));
    } else {
        accIdx = 3;
#pragma unroll
        for (int k = 0; k < BATCH * DLAT / 256; ++k) {
            const int i = k * 256 + t;
            const float m = mu[i];
            const float l = logvar[i];
            v += -0.5f * (1.0f + l - m * m - expf(l));
        }
    }

    v = blockReduceSum(v);
    if (t == 0) {
        atomicAdd(&acc[accIdx], v);
        __threadfence();
        const unsigned int done = atomicAdd(cnt, 1u);
        if (done == NRED_BLOCKS - 1) {
            const float s_pf  = atomicAdd(&acc[0], 0.0f);
            const float s_fp  = atomicAdd(&acc[1], 0.0f);
            const float s_fid = atomicAdd(&acc[2], 0.0f);
            const float s_kl  = atomicAdd(&acc[3], 0.0f);
            const float cd  = 0.5f * (s_pf / (float)(BATCH * NPTS) +
                                      s_fp / (float)(BATCH * NPTS));
            const float fid = s_fid / (float)(BATCH * PPTS);
            const float kl  = s_kl / (float)BATCH;
            out[0] = cd + 0.01f * kl + 0.5f * fid;  // CD_W=1, BETA=0.01, FID_W=0.5
            out[1] = cd;
            out[2] = kl;
            out[3] = fid;
        }
    }
}

// ---------------------------------------------------------------- launch
extern "C" void kernel_launch(void* const* d_in, const int* in_sizes, int n_in,
                              void* d_out, int out_size, void* d_ws, size_t ws_size,
                              hipStream_t stream) {
    const float* pred    = (const float*)d_in[0];
    const float* full    = (const float*)d_in[1];
    const float* partial = (const float*)d_in[2];
    const float* mu      = (const float*)d_in[3];
    const float* logvar  = (const float*)d_in[4];
    float* out = (float*)d_out;

    unsigned int* ws = (unsigned int*)d_ws;

    // 1. init workspace
    init_kernel<<<(WS_ELEMS + 255) / 256, 256, 0, stream>>>(ws);

    // 2. fused min-distance pass: 16 col chunks x (4+4+1) row tiles x 8 batches
    dim3 grid(16, 9, BATCH);
    minpass_kernel<<<grid, 256, 0, stream>>>(pred, full, partial, ws);

    // 3. all reductions + finalize in one dispatch
    reduce_finalize_kernel<<<NRED_BLOCKS, 256, 0, stream>>>(ws, mu, logvar, out);
}

// Round 5
// 127.382 us; speedup vs baseline: 1.7352x; 1.2573x over previous
//
#include <hip/hip_runtime.h>
#include <math.h>

// Problem sizes (fixed by reference setup_inputs)
#define BATCH 8
#define NPTS  8192   // pred/full points per batch
#define PPTS  2048   // partial points per batch
#define DLAT  512    // latent dim

typedef __attribute__((ext_vector_type(8)))  short short8;    // 8 bf16 (4 VGPR)
typedef __attribute__((ext_vector_type(16))) float floatx16;  // MFMA 32x32 C/D

// Workspace (floats unless noted). Each (ysplit, xblock) block OWNS its output
// slots -> plain stores, no atomics, no +inf init needed.
//   [0 .. SEG)        split-0 partial min-d^2 (pf | fp | fid regions)
//   [SEG .. 2*SEG)    split-1 partial min-d^2
//   [OFF_ACC .. +4)   acc: sum_pf, sum_fp, sum_fid, sum_kl
//   [OFF_CNT]         uint completion counter
#define SEG      (2 * BATCH * NPTS + BATCH * PPTS)   // 147456
#define DIR_PF   0
#define DIR_FP   (BATCH * NPTS)
#define DIR_FID  (2 * BATCH * NPTS)
#define OFF_ACC  (2 * SEG)
#define OFF_CNT  (OFF_ACC + 4)

#define YSPLIT 2
#define YHALF  (NPTS / YSPLIT)   // 4096 y per block
#define CHUNK  512               // y staged per LDS pass

__device__ __forceinline__ unsigned short f2bf(float f) {  // RNE float->bf16
    unsigned int u = __float_as_uint(f);
    return (unsigned short)((u + 0x7FFFu + ((u >> 16) & 1u)) >> 16);
}
__device__ __forceinline__ float bf2f(unsigned short s) {
    return __uint_as_float(((unsigned int)s) << 16);
}

// min over 16 accumulator regs (16 rows of this lane's column) + carry-in.
// fminf(fminf(a,b),c) -> v_min3_f32; 8 insts total.
__device__ __forceinline__ float min16(floatx16 d, float prev) {
    float a0 = fminf(fminf(d[0],  d[1]),  d[2]);
    float a1 = fminf(fminf(d[3],  d[4]),  d[5]);
    float a2 = fminf(fminf(d[6],  d[7]),  d[8]);
    float a3 = fminf(fminf(d[9],  d[10]), d[11]);
    float a4 = fminf(fminf(d[12], d[13]), d[14]);
    float b0 = fminf(fminf(a0, a1), a2);
    float b1 = fminf(fminf(a3, a4), d[15]);
    return fminf(fminf(b0, b1), prev);
}

// ---------------------------------------------------------------- init (tiny)
__global__ void init_acc_kernel(unsigned int* __restrict__ ws) {
    const int t = threadIdx.x;
    if (t < 4) ((float*)(ws + OFF_ACC))[t] = 0.0f;
    if (t == 4) ws[OFF_CNT] = 0u;
}

// ---------------------------------------------------------------- min pass
// Block = 256 thr = 4 waves; each wave owns 64 x (2 col-groups of 32) and
// iterates Y tiles of 32. K-slot scheme (11 of 16 used):
//   A(y): k0-2 yh | k3-5 yl | k6-8 yh | k9 yn_h | k10 yn_l | k11-15 0
//   B(x): k0-2 -2xh | k3-5 -2xh | k6-8 -2xl | k9 1 | k10 1 | k11-15 0
//   => T = |y|^2 - 2 x.y  (+ ~1e-4 split residual); |x|^2 added post-min (fp32).
__global__ __launch_bounds__(256) void minpass_kernel(
        const float* __restrict__ pred,
        const float* __restrict__ full,
        const float* __restrict__ partial,
        float* __restrict__ wsf) {
    const int bid = blockIdx.x;          // 8 batches * 72 subs * 2 ysplits
    const int ys  = bid & 1;
    const int r   = bid >> 1;
    const int b   = r / 72;
    const int s   = r % 72;

    const float* xset; const float* yset; int minoff;
    int xbase;
    if (s < 32)      { xset = pred;    yset = full; xbase = b*NPTS + s*256;
                       minoff = ys*SEG + DIR_PF  + b*NPTS + s*256; }
    else if (s < 64) { xset = full;    yset = pred; xbase = b*NPTS + (s-32)*256;
                       minoff = ys*SEG + DIR_FP  + b*NPTS + (s-32)*256; }
    else             { xset = partial; yset = pred; xbase = b*PPTS + (s-64)*256;
                       minoff = ys*SEG + DIR_FID + b*PPTS + (s-64)*256; }

    const int t    = threadIdx.x;
    const int lane = t & 63;
    const int wid  = t >> 6;
    const int l31  = lane & 31;
    const int half = lane >> 5;

    __shared__ uint4 sY[2][CHUNK];   // y records [k-half][point]  (16 KB)
    __shared__ uint4 sX[2][256];     // x records                  (8 KB)
    __shared__ float sXn[256];       // |x|^2 fp32                 (1 KB)

    // ---- x prep: thread t handles x point xbase + t
    {
        const float* xp = xset + (size_t)(xbase + t) * 3;
        const float x0 = xp[0], x1 = xp[1], x2 = xp[2];
        const float m0 = -2.0f*x0, m1 = -2.0f*x1, m2 = -2.0f*x2;
        const unsigned short h0 = f2bf(m0), h1 = f2bf(m1), h2 = f2bf(m2);
        const unsigned short l0 = f2bf(m0 - bf2f(h0));
        const unsigned short l1 = f2bf(m1 - bf2f(h1));
        const unsigned short l2 = f2bf(m2 - bf2f(h2));
        const unsigned int one = 0x3F80u;
        uint4 r0, r1;
        r0.x = (unsigned int)h0 | ((unsigned int)h1 << 16);  // k0,k1
        r0.y = (unsigned int)h2 | ((unsigned int)h0 << 16);  // k2,k3
        r0.z = (unsigned int)h1 | ((unsigned int)h2 << 16);  // k4,k5
        r0.w = (unsigned int)l0 | ((unsigned int)l1 << 16);  // k6,k7
        r1.x = (unsigned int)l2 | (one << 16);               // k8,k9
        r1.y = one;                                          // k10,k11=0
        r1.z = 0u; r1.w = 0u;
        sX[0][t] = r0; sX[1][t] = r1;
        sXn[t] = fmaf(x0, x0, fmaf(x1, x1, x2 * x2));
    }
    __syncthreads();

    const short8 bf0 = *(const short8*)&sX[half][wid*64 + l31];
    const short8 bf1 = *(const short8*)&sX[half][wid*64 + 32 + l31];
    const float  xn0 = sXn[wid*64 + l31];
    const float  xn1 = sXn[wid*64 + 32 + l31];

    const floatx16 zc = {0,0,0,0, 0,0,0,0, 0,0,0,0, 0,0,0,0};
    float cmin0 = 3.4e38f, cmin1 = 3.4e38f;

    const float* ypts = yset + (size_t)(b * NPTS + ys * YHALF) * 3;

    for (int c = 0; c < YHALF; c += CHUNK) {
        __syncthreads();  // protect sY reuse
        for (int i = t; i < CHUNK; i += 256) {
            const float* yp = ypts + (size_t)(c + i) * 3;
            const float y0 = yp[0], y1 = yp[1], y2 = yp[2];
            const unsigned short h0 = f2bf(y0), h1 = f2bf(y1), h2 = f2bf(y2);
            const unsigned short l0 = f2bf(y0 - bf2f(h0));
            const unsigned short l1 = f2bf(y1 - bf2f(h1));
            const unsigned short l2 = f2bf(y2 - bf2f(h2));
            const float yn = fmaf(y0, y0, fmaf(y1, y1, y2 * y2));
            const unsigned short nh = f2bf(yn);
            const unsigned short nl = f2bf(yn - bf2f(nh));
            uint4 r0, r1;
            r0.x = (unsigned int)h0 | ((unsigned int)h1 << 16);  // k0,k1: yh.x,yh.y
            r0.y = (unsigned int)h2 | ((unsigned int)l0 << 16);  // k2,k3: yh.z,yl.x
            r0.z = (unsigned int)l1 | ((unsigned int)l2 << 16);  // k4,k5: yl.y,yl.z
            r0.w = (unsigned int)h0 | ((unsigned int)h1 << 16);  // k6,k7: yh.x,yh.y
            r1.x = (unsigned int)h2 | ((unsigned int)nh << 16);  // k8,k9: yh.z,yn_h
            r1.y = (unsigned int)nl;                             // k10, k11=0
            r1.z = 0u; r1.w = 0u;
            sY[0][i] = r0; sY[1][i] = r1;
        }
        __syncthreads();

        for (int j = 0; j < CHUNK / 32; ++j) {
            const short8 af = *(const short8*)&sY[half][j * 32 + l31];
            const floatx16 d0 = __builtin_amdgcn_mfma_f32_32x32x16_bf16(af, bf0, zc, 0, 0, 0);
            const floatx16 d1 = __builtin_amdgcn_mfma_f32_32x32x16_bf16(af, bf1, zc, 0, 0, 0);
            cmin0 = min16(d0, cmin0);
            cmin1 = min16(d1, cmin1);
        }
    }

    // merge the two lane-halves (same column, different row halves), add |x|^2
    const float m0 = fminf(cmin0, __shfl_xor(cmin0, 32, 64));
    const float m1 = fminf(cmin1, __shfl_xor(cmin1, 32, 64));
    if (lane < 32) {
        wsf[minoff + wid*64 + l31]      = fmaxf(m0 + xn0, 0.0f);
        wsf[minoff + wid*64 + 32 + l31] = fmaxf(m1 + xn1, 0.0f);
    }
}

// ---------------------------------------------------------------- reductions
__device__ __forceinline__ float waveReduceSum(float v) {
#pragma unroll
    for (int o = 32; o > 0; o >>= 1) v += __shfl_down(v, o, 64);
    return v;
}

__device__ __forceinline__ float blockReduceSum(float v) {
    __shared__ float wsum[4];
    const int lane = threadIdx.x & 63;
    const int wid  = threadIdx.x >> 6;
    v = waveReduceSum(v);
    if (lane == 0) wsum[wid] = v;
    __syncthreads();
    if (wid == 0) {
        v = (lane < ((int)blockDim.x >> 6)) ? wsum[lane] : 0.0f;
        v = waveReduceSum(v);
    }
    return v;
}

// Blocks 0..63: pf (1024 slots each), 64..127: fp, 128..143: fid, 144: kl.
#define NRED_BLOCKS 145
__global__ __launch_bounds__(256) void reduce_finalize_kernel(
        float* __restrict__ wsf,
        const float* __restrict__ mu,
        const float* __restrict__ logvar,
        float* __restrict__ out) {
    float* acc = wsf + OFF_ACC;
    unsigned int* cnt = (unsigned int*)wsf + OFF_CNT;
    const int bid = blockIdx.x;
    const int t   = threadIdx.x;

    float v = 0.0f;
    int accIdx;
    if (bid < 144) {
        int base;
        if (bid < 64)       { accIdx = 0; base = DIR_PF  + bid * 1024;         }
        else if (bid < 128) { accIdx = 1; base = DIR_FP  + (bid - 64) * 1024;  }
        else                { accIdx = 2; base = DIR_FID + (bid - 128) * 1024; }
#pragma unroll
        for (int k = 0; k < 4; ++k) {
            const int i = base + k * 256 + t;
            const float m = fminf(wsf[i], wsf[SEG + i]);  // merge the 2 y-splits
            v += sqrtf(fmaxf(m, 1e-12f));
        }
    } else {
        accIdx = 3;
#pragma unroll
        for (int k = 0; k < BATCH * DLAT / 256; ++k) {
            const int i = k * 256 + t;
            const float m = mu[i];
            const float l = logvar[i];
            v += -0.5f * (1.0f + l - m * m - expf(l));
        }
    }

    v = blockReduceSum(v);
    if (t == 0) {
        atomicAdd(&acc[accIdx], v);
        __threadfence();
        const unsigned int done = atomicAdd(cnt, 1u);
        if (done == NRED_BLOCKS - 1) {
            const float s_pf  = atomicAdd(&acc[0], 0.0f);
            const float s_fp  = atomicAdd(&acc[1], 0.0f);
            const float s_fid = atomicAdd(&acc[2], 0.0f);
            const float s_kl  = atomicAdd(&acc[3], 0.0f);
            const float cd  = 0.5f * (s_pf / (float)(BATCH * NPTS) +
                                      s_fp / (float)(BATCH * NPTS));
            const float fid = s_fid / (float)(BATCH * PPTS);
            const float kl  = s_kl / (float)BATCH;
            out[0] = cd + 0.01f * kl + 0.5f * fid;  // CD_W=1, BETA=0.01, FID_W=0.5
            out[1] = cd;
            out[2] = kl;
            out[3] = fid;
        }
    }
}

// ---------------------------------------------------------------- launch
extern "C" void kernel_launch(void* const* d_in, const int* in_sizes, int n_in,
                              void* d_out, int out_size, void* d_ws, size_t ws_size,
                              hipStream_t stream) {
    const float* pred    = (const float*)d_in[0];
    const float* full    = (const float*)d_in[1];
    const float* partial = (const float*)d_in[2];
    const float* mu      = (const float*)d_in[3];
    const float* logvar  = (const float*)d_in[4];
    float* out = (float*)d_out;

    float* wsf = (float*)d_ws;

    // 1. tiny init (acc + counter only; min slots are block-owned plain stores)
    init_acc_kernel<<<1, 64, 0, stream>>>((unsigned int*)d_ws);

    // 2. MFMA min-distance pass: 8 batches x (32 pf + 32 fp + 8 fid) x 2 ysplits
    minpass_kernel<<<8 * 72 * YSPLIT, 256, 0, stream>>>(pred, full, partial, wsf);

    // 3. all reductions + finalize in one dispatch
    reduce_finalize_kernel<<<NRED_BLOCKS, 256, 0, stream>>>(wsf, mu, logvar, out);
}

// Round 6
// 119.863 us; speedup vs baseline: 1.8441x; 1.0627x over previous
//
#include <hip/hip_runtime.h>
#include <math.h>

// Problem sizes (fixed by reference setup_inputs)
#define BATCH 8
#define NPTS  8192   // pred/full points per batch
#define PPTS  2048   // partial points per batch
#define DLAT  512    // latent dim

typedef __attribute__((ext_vector_type(8)))  short short8;    // 8 bf16 (4 VGPR)
typedef __attribute__((ext_vector_type(16))) float floatx16;  // MFMA 32x32 C/D

// Workspace (float elements):
//   [0..4)    acc: sum_pf, sum_fp, sum_fid, sum_kl   (zeroed by minpass blk 0)
//   [4]       uint completion counter                 (zeroed by minpass blk 0)
//   [8..)     YSPLIT segments of partial min-d^2, each SEG floats
//             (pf | fp | fid regions). Block-owned plain stores, no init.
#define SEG      (2 * BATCH * NPTS + BATCH * PPTS)   // 147456
#define DIR_PF   0
#define DIR_FP   (BATCH * NPTS)
#define DIR_FID  (2 * BATCH * NPTS)
#define OFF_SEG  8

#define CHUNK 512   // y staged per LDS pass

__device__ __forceinline__ unsigned short f2bf(float f) {  // RNE float->bf16
    unsigned int u = __float_as_uint(f);
    return (unsigned short)((u + 0x7FFFu + ((u >> 16) & 1u)) >> 16);
}
__device__ __forceinline__ float bf2f(unsigned short s) {
    return __uint_as_float(((unsigned int)s) << 16);
}

// min over 16 accumulator regs (16 rows of this lane's column) + carry-in.
// fminf(fminf(a,b),c) -> v_min3_f32; 8 insts total.
__device__ __forceinline__ float min16(floatx16 d, float prev) {
    float a0 = fminf(fminf(d[0],  d[1]),  d[2]);
    float a1 = fminf(fminf(d[3],  d[4]),  d[5]);
    float a2 = fminf(fminf(d[6],  d[7]),  d[8]);
    float a3 = fminf(fminf(d[9],  d[10]), d[11]);
    float a4 = fminf(fminf(d[12], d[13]), d[14]);
    float b0 = fminf(fminf(a0, a1), a2);
    float b1 = fminf(fminf(a3, a4), d[15]);
    return fminf(fminf(b0, b1), prev);
}

// Encode one y point + its norm into two uint4 k-half records.
__device__ __forceinline__ void encodeY(float y0, float y1, float y2,
                                        uint4* r0, uint4* r1) {
    const unsigned short h0 = f2bf(y0), h1 = f2bf(y1), h2 = f2bf(y2);
    const unsigned short l0 = f2bf(y0 - bf2f(h0));
    const unsigned short l1 = f2bf(y1 - bf2f(h1));
    const unsigned short l2 = f2bf(y2 - bf2f(h2));
    const float yn = fmaf(y0, y0, fmaf(y1, y1, y2 * y2));
    const unsigned short nh = f2bf(yn);
    const unsigned short nl = f2bf(yn - bf2f(nh));
    r0->x = (unsigned int)h0 | ((unsigned int)h1 << 16);  // k0,k1: yh.x,yh.y
    r0->y = (unsigned int)h2 | ((unsigned int)l0 << 16);  // k2,k3: yh.z,yl.x
    r0->z = (unsigned int)l1 | ((unsigned int)l2 << 16);  // k4,k5: yl.y,yl.z
    r0->w = (unsigned int)h0 | ((unsigned int)h1 << 16);  // k6,k7: yh.x,yh.y
    r1->x = (unsigned int)h2 | ((unsigned int)nh << 16);  // k8,k9: yh.z,yn_h
    r1->y = (unsigned int)nl;                             // k10, k11=0
    r1->z = 0u; r1->w = 0u;
}

// ---------------------------------------------------------------- min pass
// K-slot scheme (11 of 16 used):
//   A(y): k0-2 yh | k3-5 yl | k6-8 yh | k9 yn_h | k10 yn_l | rest 0
//   B(x): k0-2 -2xh | k3-5 -2xh | k6-8 -2xl | k9 1 | k10 1 | rest 0
//   => T = |y|^2 - 2 x.y (split residual ~1e-4); |x|^2 added post-min in fp32.
// Block = 256 thr = 4 waves; wave owns 64 x (2 col-groups); j-loop fully
// unrolled with prefetched A-fragment to break the ds_read->MFMA chain.
__global__ __launch_bounds__(256) void minpass_kernel(
        const float* __restrict__ pred,
        const float* __restrict__ full,
        const float* __restrict__ partial,
        float* __restrict__ wsf,
        int ysplit) {
    const int bid = blockIdx.x;          // 8 batches * 72 subs * ysplit
    const int ys  = bid % ysplit;
    const int r   = bid / ysplit;
    const int b   = r / 72;
    const int s   = r % 72;
    const int yhalf = NPTS / ysplit;

    const int t = threadIdx.x;

    // block 0 zeroes acc + counter for the reduce kernel (ordering via stream)
    if (bid == 0) {
        if (t < 4) wsf[t] = 0.0f;
        if (t == 4) ((unsigned int*)wsf)[4] = 0u;
    }

    const float* xset; const float* yset; int minoff; int xbase;
    if (s < 32)      { xset = pred;    yset = full; xbase = b*NPTS + s*256;
                       minoff = OFF_SEG + ys*SEG + DIR_PF  + b*NPTS + s*256; }
    else if (s < 64) { xset = full;    yset = pred; xbase = b*NPTS + (s-32)*256;
                       minoff = OFF_SEG + ys*SEG + DIR_FP  + b*NPTS + (s-32)*256; }
    else             { xset = partial; yset = pred; xbase = b*PPTS + (s-64)*256;
                       minoff = OFF_SEG + ys*SEG + DIR_FID + b*PPTS + (s-64)*256; }

    const int lane = t & 63;
    const int wid  = t >> 6;
    const int l31  = lane & 31;
    const int half = lane >> 5;

    __shared__ uint4 sY[2][CHUNK];   // y records [k-half][point]  (16 KB)
    __shared__ uint4 sX[2][256];     // x records                  (8 KB)
    __shared__ float sXn[256];       // |x|^2 fp32                 (1 KB)

    // ---- x prep: thread t encodes x point xbase + t
    {
        const float* xp = xset + (size_t)(xbase + t) * 3;
        const float x0 = xp[0], x1 = xp[1], x2 = xp[2];
        const float m0 = -2.0f*x0, m1 = -2.0f*x1, m2 = -2.0f*x2;
        const unsigned short h0 = f2bf(m0), h1 = f2bf(m1), h2 = f2bf(m2);
        const unsigned short l0 = f2bf(m0 - bf2f(h0));
        const unsigned short l1 = f2bf(m1 - bf2f(h1));
        const unsigned short l2 = f2bf(m2 - bf2f(h2));
        const unsigned int one = 0x3F80u;
        uint4 r0, r1;
        r0.x = (unsigned int)h0 | ((unsigned int)h1 << 16);  // k0,k1
        r0.y = (unsigned int)h2 | ((unsigned int)h0 << 16);  // k2,k3
        r0.z = (unsigned int)h1 | ((unsigned int)h2 << 16);  // k4,k5
        r0.w = (unsigned int)l0 | ((unsigned int)l1 << 16);  // k6,k7
        r1.x = (unsigned int)l2 | (one << 16);               // k8,k9
        r1.y = one;                                          // k10,k11=0
        r1.z = 0u; r1.w = 0u;
        sX[0][t] = r0; sX[1][t] = r1;
        sXn[t] = fmaf(x0, x0, fmaf(x1, x1, x2 * x2));
    }
    __syncthreads();

    const short8 bf0 = *(const short8*)&sX[half][wid*64 + l31];
    const short8 bf1 = *(const short8*)&sX[half][wid*64 + 32 + l31];
    const float  xn0 = sXn[wid*64 + l31];
    const float  xn1 = sXn[wid*64 + 32 + l31];

    const floatx16 zc = {0,0,0,0, 0,0,0,0, 0,0,0,0, 0,0,0,0};
    float cmin0 = 3.4e38f, cmin1 = 3.4e38f;

    const float* ypts = yset + (size_t)(b * NPTS + ys * yhalf) * 3;

    for (int c = 0; c < yhalf; c += CHUNK) {
        __syncthreads();  // protect sY reuse
        // stage 512 y points: thread t encodes points 2t, 2t+1 (24B = 3 float2)
        {
            const float2* yp2 = (const float2*)(ypts + (size_t)(c + 2 * t) * 3);
            const float2 pa = yp2[0], pb = yp2[1], pc = yp2[2];
            uint4 r0, r1;
            encodeY(pa.x, pa.y, pb.x, &r0, &r1);
            sY[0][2*t]   = r0; sY[1][2*t]   = r1;
            encodeY(pb.y, pc.x, pc.y, &r0, &r1);
            sY[0][2*t+1] = r0; sY[1][2*t+1] = r1;
        }
        __syncthreads();

        const uint4* sYh = &sY[half][0];
        short8 af = *(const short8*)&sYh[l31];
#pragma unroll
        for (int j = 0; j < CHUNK / 32; ++j) {
            short8 afn = af;
            if (j + 1 < CHUNK / 32)                    // static under unroll
                afn = *(const short8*)&sYh[(j + 1) * 32 + l31];
            const floatx16 d0 = __builtin_amdgcn_mfma_f32_32x32x16_bf16(af, bf0, zc, 0, 0, 0);
            const floatx16 d1 = __builtin_amdgcn_mfma_f32_32x32x16_bf16(af, bf1, zc, 0, 0, 0);
            cmin0 = min16(d0, cmin0);
            cmin1 = min16(d1, cmin1);
            af = afn;
        }
    }

    // merge the two lane-halves (same column, different row halves), add |x|^2
    const float m0 = fminf(cmin0, __shfl_xor(cmin0, 32, 64));
    const float m1 = fminf(cmin1, __shfl_xor(cmin1, 32, 64));
    if (lane < 32) {
        wsf[minoff + wid*64 + l31]      = fmaxf(m0 + xn0, 0.0f);
        wsf[minoff + wid*64 + 32 + l31] = fmaxf(m1 + xn1, 0.0f);
    }
}

// ---------------------------------------------------------------- reductions
__device__ __forceinline__ float waveReduceSum(float v) {
#pragma unroll
    for (int o = 32; o > 0; o >>= 1) v += __shfl_down(v, o, 64);
    return v;
}

__device__ __forceinline__ float blockReduceSum(float v) {
    __shared__ float wsum[4];
    const int lane = threadIdx.x & 63;
    const int wid  = threadIdx.x >> 6;
    v = waveReduceSum(v);
    if (lane == 0) wsum[wid] = v;
    __syncthreads();
    if (wid == 0) {
        v = (lane < ((int)blockDim.x >> 6)) ? wsum[lane] : 0.0f;
        v = waveReduceSum(v);
    }
    return v;
}

// Blocks 0..63: pf (1024 slots each), 64..127: fp, 128..143: fid, 144: kl.
#define NRED_BLOCKS 145
__global__ __launch_bounds__(256) void reduce_finalize_kernel(
        float* __restrict__ wsf,
        const float* __restrict__ mu,
        const float* __restrict__ logvar,
        float* __restrict__ out,
        int ysplit) {
    float* acc = wsf;
    unsigned int* cnt = (unsigned int*)wsf + 4;
    const int bid = blockIdx.x;
    const int t   = threadIdx.x;

    float v = 0.0f;
    int accIdx;
    if (bid < 144) {
        int base;
        if (bid < 64)       { accIdx = 0; base = DIR_PF  + bid * 1024;         }
        else if (bid < 128) { accIdx = 1; base = DIR_FP  + (bid - 64) * 1024;  }
        else                { accIdx = 2; base = DIR_FID + (bid - 128) * 1024; }
#pragma unroll
        for (int k = 0; k < 4; ++k) {
            const int i = OFF_SEG + base + k * 256 + t;
            float m = wsf[i];
            for (int sg = 1; sg < ysplit; ++sg) m = fminf(m, wsf[sg * SEG + i]);
            v += sqrtf(fmaxf(m, 1e-12f));
        }
    } else {
        accIdx = 3;
#pragma unroll
        for (int k = 0; k < BATCH * DLAT / 256; ++k) {
            const int i = k * 256 + t;
            const float m = mu[i];
            const float l = logvar[i];
            v += -0.5f * (1.0f + l - m * m - expf(l));
        }
    }

    v = blockReduceSum(v);
    if (t == 0) {
        atomicAdd(&acc[accIdx], v);
        __threadfence();
        const unsigned int done = atomicAdd(cnt, 1u);
        if (done == NRED_BLOCKS - 1) {
            const float s_pf  = atomicAdd(&acc[0], 0.0f);
            const float s_fp  = atomicAdd(&acc[1], 0.0f);
            const float s_fid = atomicAdd(&acc[2], 0.0f);
            const float s_kl  = atomicAdd(&acc[3], 0.0f);
            const float cd  = 0.5f * (s_pf / (float)(BATCH * NPTS) +
                                      s_fp / (float)(BATCH * NPTS));
            const float fid = s_fid / (float)(BATCH * PPTS);
            const float kl  = s_kl / (float)BATCH;
            out[0] = cd + 0.01f * kl + 0.5f * fid;  // CD_W=1, BETA=0.01, FID_W=0.5
            out[1] = cd;
            out[2] = kl;
            out[3] = fid;
        }
    }
}

// ---------------------------------------------------------------- launch
extern "C" void kernel_launch(void* const* d_in, const int* in_sizes, int n_in,
                              void* d_out, int out_size, void* d_ws, size_t ws_size,
                              hipStream_t stream) {
    const float* pred    = (const float*)d_in[0];
    const float* full    = (const float*)d_in[1];
    const float* partial = (const float*)d_in[2];
    const float* mu      = (const float*)d_in[3];
    const float* logvar  = (const float*)d_in[4];
    float* out = (float*)d_out;
    float* wsf = (float*)d_ws;

    // ysplit chosen from ws capacity (deterministic: ws_size fixed across calls)
    const size_t need4 = (size_t)(OFF_SEG + 4 * SEG) * 4;
    const int ysplit = (ws_size >= need4) ? 4 : 2;

    // 1. MFMA min-distance pass (block 0 also zeroes acc+counter)
    minpass_kernel<<<8 * 72 * ysplit, 256, 0, stream>>>(pred, full, partial, wsf, ysplit);

    // 2. all reductions + finalize in one dispatch
    reduce_finalize_kernel<<<NRED_BLOCKS, 256, 0, stream>>>(wsf, mu, logvar, out, ysplit);
}

// Round 7
// 103.917 us; speedup vs baseline: 2.1271x; 1.1534x over previous
//
#include <hip/hip_runtime.h>
#include <math.h>

// Problem sizes (fixed by reference setup_inputs)
#define BATCH 8
#define NPTS  8192   // pred/full points per batch
#define PPTS  2048   // partial points per batch
#define DLAT  512    // latent dim

typedef __attribute__((ext_vector_type(8)))  short short8;    // 8 bf16 (4 VGPR)
typedef __attribute__((ext_vector_type(16))) float floatx16;  // MFMA 32x32 C/D

// Workspace (float elements):
//   [0..4)    acc: sum_pf, sum_fp, sum_fid, sum_kl   (zeroed by minpass blk 0)
//   [4]       uint completion counter                 (zeroed by minpass blk 0)
//   [8..)     YSPLIT segments of partial min-d^2, each SEG floats
//             (pf | fp | fid regions). Block-owned plain stores, no init.
#define SEG      (2 * BATCH * NPTS + BATCH * PPTS)   // 147456
#define DIR_PF   0
#define DIR_FP   (BATCH * NPTS)
#define DIR_FID  (2 * BATCH * NPTS)
#define OFF_SEG  8

#define CHUNK  512   // y staged per LDS pass
#define XBLK   512   // x points per block (4 waves x 4 col-groups of 32)

__device__ __forceinline__ unsigned short f2bf(float f) {  // RNE float->bf16
    unsigned int u = __float_as_uint(f);
    return (unsigned short)((u + 0x7FFFu + ((u >> 16) & 1u)) >> 16);
}
__device__ __forceinline__ float bf2f(unsigned short s) {
    return __uint_as_float(((unsigned int)s) << 16);
}

// min over 16 accumulator regs (16 rows of this lane's column) + carry-in.
__device__ __forceinline__ float min16(floatx16 d, float prev) {
    float a0 = fminf(fminf(d[0],  d[1]),  d[2]);
    float a1 = fminf(fminf(d[3],  d[4]),  d[5]);
    float a2 = fminf(fminf(d[6],  d[7]),  d[8]);
    float a3 = fminf(fminf(d[9],  d[10]), d[11]);
    float a4 = fminf(fminf(d[12], d[13]), d[14]);
    float b0 = fminf(fminf(a0, a1), a2);
    float b1 = fminf(fminf(a3, a4), d[15]);
    return fminf(fminf(b0, b1), prev);
}

// Encode one y point + its norm into two uint4 k-half records.
__device__ __forceinline__ void encodeY(float y0, float y1, float y2,
                                        uint4* r0, uint4* r1) {
    const unsigned short h0 = f2bf(y0), h1 = f2bf(y1), h2 = f2bf(y2);
    const unsigned short l0 = f2bf(y0 - bf2f(h0));
    const unsigned short l1 = f2bf(y1 - bf2f(h1));
    const unsigned short l2 = f2bf(y2 - bf2f(h2));
    const float yn = fmaf(y0, y0, fmaf(y1, y1, y2 * y2));
    const unsigned short nh = f2bf(yn);
    const unsigned short nl = f2bf(yn - bf2f(nh));
    r0->x = (unsigned int)h0 | ((unsigned int)h1 << 16);  // k0,k1: yh.x,yh.y
    r0->y = (unsigned int)h2 | ((unsigned int)l0 << 16);  // k2,k3: yh.z,yl.x
    r0->z = (unsigned int)l1 | ((unsigned int)l2 << 16);  // k4,k5: yl.y,yl.z
    r0->w = (unsigned int)h0 | ((unsigned int)h1 << 16);  // k6,k7: yh.x,yh.y
    r1->x = (unsigned int)h2 | ((unsigned int)nh << 16);  // k8,k9: yh.z,yn_h
    r1->y = (unsigned int)nl;                             // k10, k11=0
    r1->z = 0u; r1->w = 0u;
}

// ---------------------------------------------------------------- min pass
// K-slot scheme (11 of 16 used):
//   A(y): k0-2 yh | k3-5 yl | k6-8 yh | k9 yn_h | k10 yn_l | rest 0
//   B(x): k0-2 -2xh | k3-5 -2xh | k6-8 -2xl | k9 1 | k10 1 | rest 0
//   => T = |y|^2 - 2 x.y (split residual ~1e-4); |x|^2 added post-min in fp32.
// Block = 256 thr = 4 waves; block owns 512 x; wave owns 128 x (4 col-groups)
// so each staged A-fragment feeds 4 MFMAs. launch_bounds(256,4) gives a
// 128-VGPR budget so MFMA accumulators stay in VGPRs (no accvgpr moves).
__global__ __launch_bounds__(256, 4) void minpass_kernel(
        const float* __restrict__ pred,
        const float* __restrict__ full,
        const float* __restrict__ partial,
        float* __restrict__ wsf,
        int ysplit) {
    const int bid = blockIdx.x;          // 8 batches * 36 subs * ysplit
    const int ys  = bid % ysplit;
    const int r   = bid / ysplit;
    const int b   = r / 36;
    const int s   = r % 36;
    const int yhalf = NPTS / ysplit;

    const int t = threadIdx.x;

    // block 0 zeroes acc + counter for the reduce kernel (stream ordering)
    if (bid == 0) {
        if (t < 4) wsf[t] = 0.0f;
        if (t == 4) ((unsigned int*)wsf)[4] = 0u;
    }

    const float* xset; const float* yset; int minoff; int xbase;
    if (s < 16)      { xset = pred;    yset = full; xbase = b*NPTS + s*XBLK;
                       minoff = OFF_SEG + ys*SEG + DIR_PF  + b*NPTS + s*XBLK; }
    else if (s < 32) { xset = full;    yset = pred; xbase = b*NPTS + (s-16)*XBLK;
                       minoff = OFF_SEG + ys*SEG + DIR_FP  + b*NPTS + (s-16)*XBLK; }
    else             { xset = partial; yset = pred; xbase = b*PPTS + (s-32)*XBLK;
                       minoff = OFF_SEG + ys*SEG + DIR_FID + b*PPTS + (s-32)*XBLK; }

    const int lane = t & 63;
    const int wid  = t >> 6;
    const int l31  = lane & 31;
    const int half = lane >> 5;

    __shared__ uint4 sY[2][CHUNK];   // y records [k-half][point]  (16 KB)
    __shared__ uint4 sX[2][XBLK];    // x records                  (16 KB)
    __shared__ float sXn[XBLK];      // |x|^2 fp32                 (2 KB)

    // ---- x prep: thread encodes x points t and t+256 (16B-stride writes)
    for (int i = t; i < XBLK; i += 256) {
        const float* xp = xset + (size_t)(xbase + i) * 3;
        const float x0 = xp[0], x1 = xp[1], x2 = xp[2];
        const float m0 = -2.0f*x0, m1 = -2.0f*x1, m2 = -2.0f*x2;
        const unsigned short h0 = f2bf(m0), h1 = f2bf(m1), h2 = f2bf(m2);
        const unsigned short l0 = f2bf(m0 - bf2f(h0));
        const unsigned short l1 = f2bf(m1 - bf2f(h1));
        const unsigned short l2 = f2bf(m2 - bf2f(h2));
        const unsigned int one = 0x3F80u;
        uint4 r0, r1;
        r0.x = (unsigned int)h0 | ((unsigned int)h1 << 16);  // k0,k1
        r0.y = (unsigned int)h2 | ((unsigned int)h0 << 16);  // k2,k3
        r0.z = (unsigned int)h1 | ((unsigned int)h2 << 16);  // k4,k5
        r0.w = (unsigned int)l0 | ((unsigned int)l1 << 16);  // k6,k7
        r1.x = (unsigned int)l2 | (one << 16);               // k8,k9
        r1.y = one;                                          // k10,k11=0
        r1.z = 0u; r1.w = 0u;
        sX[0][i] = r0; sX[1][i] = r1;
        sXn[i] = fmaf(x0, x0, fmaf(x1, x1, x2 * x2));
    }
    __syncthreads();

    const int xw = wid * 128;
    const short8 bf0 = *(const short8*)&sX[half][xw + l31];
    const short8 bf1 = *(const short8*)&sX[half][xw + 32 + l31];
    const short8 bf2 = *(const short8*)&sX[half][xw + 64 + l31];
    const short8 bf3 = *(const short8*)&sX[half][xw + 96 + l31];
    const float  xn0 = sXn[xw + l31];
    const float  xn1 = sXn[xw + 32 + l31];
    const float  xn2 = sXn[xw + 64 + l31];
    const float  xn3 = sXn[xw + 96 + l31];

    const floatx16 zc = {0,0,0,0, 0,0,0,0, 0,0,0,0, 0,0,0,0};
    float cmin0 = 3.4e38f, cmin1 = 3.4e38f, cmin2 = 3.4e38f, cmin3 = 3.4e38f;

    const float* ypts = yset + (size_t)(b * NPTS + ys * yhalf) * 3;

    for (int c = 0; c < yhalf; c += CHUNK) {
        __syncthreads();  // protect sY reuse
        // stage: thread t encodes chunk points t and t+256 (16B-stride writes)
        for (int i = t; i < CHUNK; i += 256) {
            const float* yp = ypts + (size_t)(c + i) * 3;
            uint4 r0, r1;
            encodeY(yp[0], yp[1], yp[2], &r0, &r1);
            sY[0][i] = r0; sY[1][i] = r1;
        }
        __syncthreads();

        const uint4* sYh = &sY[half][0];
        short8 af = *(const short8*)&sYh[l31];
#pragma unroll
        for (int j = 0; j < CHUNK / 32; ++j) {
            short8 afn = af;
            if (j + 1 < CHUNK / 32)                    // static under unroll
                afn = *(const short8*)&sYh[(j + 1) * 32 + l31];
            // staggered: keep <=2 accumulators live, overlap MFMA with min tree
            const floatx16 d0 = __builtin_amdgcn_mfma_f32_32x32x16_bf16(af, bf0, zc, 0, 0, 0);
            const floatx16 d1 = __builtin_amdgcn_mfma_f32_32x32x16_bf16(af, bf1, zc, 0, 0, 0);
            cmin0 = min16(d0, cmin0);
            const floatx16 d2 = __builtin_amdgcn_mfma_f32_32x32x16_bf16(af, bf2, zc, 0, 0, 0);
            cmin1 = min16(d1, cmin1);
            const floatx16 d3 = __builtin_amdgcn_mfma_f32_32x32x16_bf16(af, bf3, zc, 0, 0, 0);
            cmin2 = min16(d2, cmin2);
            cmin3 = min16(d3, cmin3);
            af = afn;
        }
    }

    // merge the two lane-halves (same column, different row halves), add |x|^2
    const float m0 = fminf(cmin0, __shfl_xor(cmin0, 32, 64));
    const float m1 = fminf(cmin1, __shfl_xor(cmin1, 32, 64));
    const float m2 = fminf(cmin2, __shfl_xor(cmin2, 32, 64));
    const float m3 = fminf(cmin3, __shfl_xor(cmin3, 32, 64));
    if (lane < 32) {
        wsf[minoff + xw + l31]      = fmaxf(m0 + xn0, 0.0f);
        wsf[minoff + xw + 32 + l31] = fmaxf(m1 + xn1, 0.0f);
        wsf[minoff + xw + 64 + l31] = fmaxf(m2 + xn2, 0.0f);
        wsf[minoff + xw + 96 + l31] = fmaxf(m3 + xn3, 0.0f);
    }
}

// ---------------------------------------------------------------- reductions
__device__ __forceinline__ float waveReduceSum(float v) {
#pragma unroll
    for (int o = 32; o > 0; o >>= 1) v += __shfl_down(v, o, 64);
    return v;
}

__device__ __forceinline__ float blockReduceSum(float v) {
    __shared__ float wsum[4];
    const int lane = threadIdx.x & 63;
    const int wid  = threadIdx.x >> 6;
    v = waveReduceSum(v);
    if (lane == 0) wsum[wid] = v;
    __syncthreads();
    if (wid == 0) {
        v = (lane < ((int)blockDim.x >> 6)) ? wsum[lane] : 0.0f;
        v = waveReduceSum(v);
    }
    return v;
}

// Blocks 0..63: pf (1024 slots each), 64..127: fp, 128..143: fid, 144: kl.
#define NRED_BLOCKS 145
__global__ __launch_bounds__(256) void reduce_finalize_kernel(
        float* __restrict__ wsf,
        const float* __restrict__ mu,
        const float* __restrict__ logvar,
        float* __restrict__ out,
        int ysplit) {
    float* acc = wsf;
    unsigned int* cnt = (unsigned int*)wsf + 4;
    const int bid = blockIdx.x;
    const int t   = threadIdx.x;

    float v = 0.0f;
    int accIdx;
    if (bid < 144) {
        int base;
        if (bid < 64)       { accIdx = 0; base = DIR_PF  + bid * 1024;         }
        else if (bid < 128) { accIdx = 1; base = DIR_FP  + (bid - 64) * 1024;  }
        else                { accIdx = 2; base = DIR_FID + (bid - 128) * 1024; }
#pragma unroll
        for (int k = 0; k < 4; ++k) {
            const int i = OFF_SEG + base + k * 256 + t;
            float m = wsf[i];
            for (int sg = 1; sg < ysplit; ++sg) m = fminf(m, wsf[sg * SEG + i]);
            v += sqrtf(fmaxf(m, 1e-12f));
        }
    } else {
        accIdx = 3;
#pragma unroll
        for (int k = 0; k < BATCH * DLAT / 256; ++k) {
            const int i = k * 256 + t;
            const float m = mu[i];
            const float l = logvar[i];
            v += -0.5f * (1.0f + l - m * m - expf(l));
        }
    }

    v = blockReduceSum(v);
    if (t == 0) {
        atomicAdd(&acc[accIdx], v);
        __threadfence();
        const unsigned int done = atomicAdd(cnt, 1u);
        if (done == NRED_BLOCKS - 1) {
            const float s_pf  = atomicAdd(&acc[0], 0.0f);
            const float s_fp  = atomicAdd(&acc[1], 0.0f);
            const float s_fid = atomicAdd(&acc[2], 0.0f);
            const float s_kl  = atomicAdd(&acc[3], 0.0f);
            const float cd  = 0.5f * (s_pf / (float)(BATCH * NPTS) +
                                      s_fp / (float)(BATCH * NPTS));
            const float fid = s_fid / (float)(BATCH * PPTS);
            const float kl  = s_kl / (float)BATCH;
            out[0] = cd + 0.01f * kl + 0.5f * fid;  // CD_W=1, BETA=0.01, FID_W=0.5
            out[1] = cd;
            out[2] = kl;
            out[3] = fid;
        }
    }
}

// ---------------------------------------------------------------- launch
extern "C" void kernel_launch(void* const* d_in, const int* in_sizes, int n_in,
                              void* d_out, int out_size, void* d_ws, size_t ws_size,
                              hipStream_t stream) {
    const float* pred    = (const float*)d_in[0];
    const float* full    = (const float*)d_in[1];
    const float* partial = (const float*)d_in[2];
    const float* mu      = (const float*)d_in[3];
    const float* logvar  = (const float*)d_in[4];
    float* out = (float*)d_out;
    float* wsf = (float*)d_ws;

    // ysplit chosen from ws capacity (deterministic: ws_size fixed across calls)
    const size_t need4 = (size_t)(OFF_SEG + 4 * SEG) * 4;
    const int ysplit = (ws_size >= need4) ? 4 : 2;

    // 1. MFMA min-distance pass (block 0 also zeroes acc+counter)
    minpass_kernel<<<8 * 36 * ysplit, 256, 0, stream>>>(pred, full, partial, wsf, ysplit);

    // 2. all reductions + finalize in one dispatch
    reduce_finalize_kernel<<<NRED_BLOCKS, 256, 0, stream>>>(wsf, mu, logvar, out, ysplit);
}